// Round 3
// baseline (4243.502 us; speedup 1.0000x reference)
//
#include <hip/hip_runtime.h>
#include <hip/hip_bf16.h>

constexpr int N_NODES = 100000;
constexpr int N_REL   = 3;
constexpr int N_EDGE  = 1600000;

// ---------------- graph preprocessing ----------------

__global__ void degree_kernel(const int* __restrict__ src, const int* __restrict__ dst,
                              int* __restrict__ deg_out, int* __restrict__ deg_in) {
  int tid = blockIdx.x * blockDim.x + threadIdx.x;
  if (tid >= N_REL * N_EDGE) return;
  int r = tid / N_EDGE;
  atomicAdd(&deg_out[r * N_NODES + src[tid]], 1);
  atomicAdd(&deg_in [r * N_NODES + dst[tid]], 1);
}

__global__ void inv_kernel(const int* __restrict__ deg_out, const int* __restrict__ deg_in,
                           float* __restrict__ inv_out, float* __restrict__ inv_in) {
  int i = blockIdx.x * blockDim.x + threadIdx.x;
  if (i >= N_REL * N_NODES) return;
  inv_out[i] = rsqrtf(fmaxf((float)deg_out[i], 1.0f));
  inv_in[i]  = rsqrtf(fmaxf((float)deg_in[i],  1.0f));
}

// one block per relation; exclusive scan of in-degrees -> CSR row offsets
__global__ void scan_kernel(const int* __restrict__ deg_in, int* __restrict__ row_off,
                            int* __restrict__ cursor) {
  int r = blockIdx.x;
  const int* d = deg_in + r * N_NODES;
  int* ro  = row_off + r * (N_NODES + 1);
  int* cur = cursor  + r * N_NODES;
  __shared__ int smem[1024];
  __shared__ int sbase;
  if (threadIdx.x == 0) sbase = 0;
  __syncthreads();
  for (int base = 0; base < N_NODES; base += 1024) {
    int i = base + (int)threadIdx.x;
    int v = (i < N_NODES) ? d[i] : 0;
    smem[threadIdx.x] = v;
    __syncthreads();
    for (int off = 1; off < 1024; off <<= 1) {
      int t = (threadIdx.x >= off) ? smem[threadIdx.x - off] : 0;
      __syncthreads();
      smem[threadIdx.x] += t;
      __syncthreads();
    }
    int excl = smem[threadIdx.x] - v;
    int myb = sbase;
    if (i < N_NODES) { ro[i] = myb + excl; cur[i] = myb + excl; }
    int tot = smem[1023];
    __syncthreads();
    if (threadIdx.x == 0) sbase += tot;
    __syncthreads();
  }
  if (threadIdx.x == 0) ro[N_NODES] = sbase;   // == N_EDGE
}

// write interleaved (src_as_float, coef) per sorted edge slot
__global__ void bucket_kernel(const int* __restrict__ src, const int* __restrict__ dst,
                              const float* __restrict__ inv_out, const float* __restrict__ inv_in,
                              int* __restrict__ cursor, float2* __restrict__ sorted_sc) {
  int tid = blockIdx.x * blockDim.x + threadIdx.x;
  if (tid >= N_REL * N_EDGE) return;
  int r = tid / N_EDGE;
  int s = src[tid], d = dst[tid];
  int pos = atomicAdd(&cursor[r * N_NODES + d], 1);
  size_t o = (size_t)r * N_EDGE + pos;
  float coef = inv_out[r * N_NODES + s] * inv_in[r * N_NODES + d];
  sorted_sc[o] = make_float2(__int_as_float(s), coef);
}

// ---------------- per-layer kernels ----------------

// Gather-first: agg[n][r*128 + c] = sum_{e in CSR_r(n)} coef_e * h[src_e][c]
// One wave per (node, relation); 64 lanes x float2 cover 128 cols.
// Gather source = h (51 MB) shared by all 3 relation slices -> LLC-resident.
__launch_bounds__(256)
__global__ void agg_kernel(const float* __restrict__ h, const float2* __restrict__ sc,
                           const int* __restrict__ row_off, float* __restrict__ agg) {
  int r    = blockIdx.y;
  int node = blockIdx.x * 4 + ((int)threadIdx.x >> 6);
  int lane = (int)threadIdx.x & 63;
  if (node >= N_NODES) return;
  const int* ro = row_off + r * (N_NODES + 1);
  int beg = ro[node], end = ro[node + 1];
  const float2* scp = sc + (size_t)r * N_EDGE;
  const float2* hp  = (const float2*)h + lane;   // row = 64 float2
  float2 acc = make_float2(0.f, 0.f);
  int e = beg;
  for (; e + 4 <= end; e += 4) {
    float2 q0 = scp[e+0], q1 = scp[e+1], q2 = scp[e+2], q3 = scp[e+3];
    float2 v0 = hp[(size_t)__float_as_int(q0.x) * 64];
    float2 v1 = hp[(size_t)__float_as_int(q1.x) * 64];
    float2 v2 = hp[(size_t)__float_as_int(q2.x) * 64];
    float2 v3 = hp[(size_t)__float_as_int(q3.x) * 64];
    acc.x = fmaf(q0.y, v0.x, acc.x); acc.y = fmaf(q0.y, v0.y, acc.y);
    acc.x = fmaf(q1.y, v1.x, acc.x); acc.y = fmaf(q1.y, v1.y, acc.y);
    acc.x = fmaf(q2.y, v2.x, acc.x); acc.y = fmaf(q2.y, v2.y, acc.y);
    acc.x = fmaf(q3.y, v3.x, acc.x); acc.y = fmaf(q3.y, v3.y, acc.y);
  }
  for (; e < end; e++) {
    float2 q = scp[e];
    float2 v = hp[(size_t)__float_as_int(q.x) * 64];
    acc.x = fmaf(q.y, v.x, acc.x); acc.y = fmaf(q.y, v.y, acc.y);
  }
  ((float2*)(agg + (size_t)node * 384 + r * 128))[lane] = acc;
}

// out[n][:] = relu?( agg[n][0:384] @ Wcat[384][DO] + sum_r b[r][:] )
template<int DO>
__launch_bounds__(256)
__global__ void gemm_kernel(const float* __restrict__ A, const float* __restrict__ W,
                            const float* __restrict__ b, float* __restrict__ out, int apply_relu) {
  constexpr int TN = DO / 16;      // cols per thread (8 or 4)
  constexpr int K  = 384;
  int m0 = blockIdx.x * 128;
  int tid = threadIdx.x;
  int tx = tid & 15;               // col group
  int ty = tid >> 4;               // row group
  __shared__ float As[128][17];
  __shared__ float Bs[16][DO];
  float acc[8][TN];
  #pragma unroll
  for (int i = 0; i < 8; i++)
    #pragma unroll
    for (int j = 0; j < TN; j++) acc[i][j] = 0.f;

  for (int k0 = 0; k0 < K; k0 += 16) {
    #pragma unroll
    for (int idx = tid; idx < 128 * 16; idx += 256) {
      int row = idx >> 4, kk = idx & 15;
      float v = 0.f;
      if (m0 + row < N_NODES) v = A[(size_t)(m0 + row) * K + k0 + kk];
      As[row][kk] = v;
    }
    #pragma unroll
    for (int idx = tid; idx < 16 * DO; idx += 256) {
      int kk = idx / DO, c = idx % DO;
      Bs[kk][c] = W[(size_t)(k0 + kk) * DO + c];
    }
    __syncthreads();
    #pragma unroll
    for (int kk = 0; kk < 16; kk++) {
      float a[8], bv[TN];
      #pragma unroll
      for (int i = 0; i < 8; i++) a[i] = As[ty * 8 + i][kk];
      #pragma unroll
      for (int j = 0; j < TN; j++) bv[j] = Bs[kk][tx * TN + j];
      #pragma unroll
      for (int i = 0; i < 8; i++)
        #pragma unroll
        for (int j = 0; j < TN; j++) acc[i][j] = fmaf(a[i], bv[j], acc[i][j]);
    }
    __syncthreads();
  }
  float bias[TN];
  #pragma unroll
  for (int j = 0; j < TN; j++) {
    int c = tx * TN + j;
    bias[j] = b[0 * DO + c] + b[1 * DO + c] + b[2 * DO + c];
  }
  #pragma unroll
  for (int i = 0; i < 8; i++) {
    int row = m0 + ty * 8 + i;
    if (row < N_NODES) {
      float* yp = out + (size_t)row * DO + tx * TN;
      #pragma unroll
      for (int j = 0; j < TN; j += 4) {
        float4 v = make_float4(acc[i][j] + bias[j], acc[i][j+1] + bias[j+1],
                               acc[i][j+2] + bias[j+2], acc[i][j+3] + bias[j+3]);
        if (apply_relu) {
          v.x = fmaxf(v.x, 0.f); v.y = fmaxf(v.y, 0.f);
          v.z = fmaxf(v.z, 0.f); v.w = fmaxf(v.w, 0.f);
        }
        *(float4*)(yp + j) = v;
      }
    }
  }
}

// ---------------- launch ----------------

extern "C" void kernel_launch(void* const* d_in, const int* in_sizes, int n_in,
                              void* d_out, int out_size, void* d_ws, size_t ws_size,
                              hipStream_t stream) {
  const float* x   = (const float*)d_in[0];
  const int*   src = (const int*)d_in[1];
  const int*   dst = (const int*)d_in[2];
  const float* Wl[6]; const float* bl[6];
  for (int i = 0; i < 6; i++) { Wl[i] = (const float*)d_in[3 + 2*i]; bl[i] = (const float*)d_in[4 + 2*i]; }

  char* ws = (char*)d_ws;
  size_t off = 0;
  auto take = [&](size_t bytes) -> char* {
    char* p = ws + off;
    off = (off + bytes + 255) & ~(size_t)255;
    return p;
  };
  float*  h       = (float*)take((size_t)N_NODES * 128 * 4);
  float*  aggbuf  = (float*)take((size_t)N_NODES * 384 * 4);
  int*    deg     = (int*)  take((size_t)2 * N_REL * N_NODES * 4);   // deg_out | deg_in
  int*    deg_out = deg;
  int*    deg_in  = deg + N_REL * N_NODES;
  float*  inv_out = (float*)take((size_t)N_REL * N_NODES * 4);
  float*  inv_in  = (float*)take((size_t)N_REL * N_NODES * 4);
  int*    row_off = (int*)  take((size_t)N_REL * (N_NODES + 1) * 4);
  int*    cursor  = (int*)  take((size_t)N_REL * N_NODES * 4);
  float2* s_sc    = (float2*)take((size_t)N_REL * N_EDGE * 8);
  (void)ws_size; (void)in_sizes; (void)n_in; (void)out_size;

  hipMemsetAsync(deg, 0, (size_t)2 * N_REL * N_NODES * 4, stream);

  const int eblocks = (N_REL * N_EDGE + 255) / 256;
  const int nblocks = (N_REL * N_NODES + 255) / 256;
  degree_kernel<<<eblocks, 256, 0, stream>>>(src, dst, deg_out, deg_in);
  inv_kernel<<<nblocks, 256, 0, stream>>>(deg_out, deg_in, inv_out, inv_in);
  scan_kernel<<<N_REL, 1024, 0, stream>>>(deg_in, row_off, cursor);
  bucket_kernel<<<eblocks, 256, 0, stream>>>(src, dst, inv_out, inv_in, cursor, s_sc);

  const int mtiles = (N_NODES + 127) / 128;
  const int agg_blocks = (N_NODES + 3) / 4;
  const float* h_in = x;
  for (int L = 0; L < 6; L++) {
    agg_kernel<<<dim3(agg_blocks, 3), 256, 0, stream>>>(h_in, s_sc, row_off, aggbuf);
    if (L < 5) {
      gemm_kernel<128><<<mtiles, 256, 0, stream>>>(aggbuf, Wl[L], bl[L], h, 1);
      h_in = h;
    } else {
      gemm_kernel<64><<<mtiles, 256, 0, stream>>>(aggbuf, Wl[L], bl[L], (float*)d_out, 0);
    }
  }
}

// Round 5
// 3497.585 us; speedup vs baseline: 1.2133x; 1.2133x over previous
//
#include <hip/hip_runtime.h>
#include <hip/hip_bf16.h>

constexpr int N_NODES = 100000;
constexpr int N_REL   = 3;
constexpr int N_EDGE  = 1600000;
constexpr int NCHUNK  = (N_NODES + 1023) / 1024;   // 98

// ---------------- graph preprocessing ----------------

// One pass: in-degree atomic returns each edge's within-bucket position;
// out-degree atomic counts only. 9.6M atomics total (the write-through floor).
__global__ void p1_kernel(const int* __restrict__ src, const int* __restrict__ dst,
                          int* __restrict__ deg_out, int* __restrict__ deg_in,
                          int* __restrict__ pos) {
  int tid = blockIdx.x * blockDim.x + threadIdx.x;
  if (tid >= N_REL * N_EDGE) return;
  int r = tid / N_EDGE;
  pos[tid] = atomicAdd(&deg_in[r * N_NODES + dst[tid]], 1);
  atomicAdd(&deg_out[r * N_NODES + src[tid]], 1);
}

__global__ void inv_kernel(const int* __restrict__ deg_out, const int* __restrict__ deg_in,
                           float* __restrict__ inv_out, float* __restrict__ inv_in) {
  int i = blockIdx.x * blockDim.x + threadIdx.x;
  if (i >= N_REL * N_NODES) return;
  inv_out[i] = rsqrtf(fmaxf((float)deg_out[i], 1.0f));
  inv_in[i]  = rsqrtf(fmaxf((float)deg_in[i],  1.0f));
}

// scan phase 1: per-1024-chunk exclusive scan + chunk totals
__global__ void scan1_kernel(const int* __restrict__ deg_in, int* __restrict__ excl,
                             int* __restrict__ part) {
  int r = blockIdx.y;
  int i = blockIdx.x * 1024 + threadIdx.x;
  int v = (i < N_NODES) ? deg_in[r * N_NODES + i] : 0;
  __shared__ int sm[1024];
  sm[threadIdx.x] = v;
  __syncthreads();
  for (int off = 1; off < 1024; off <<= 1) {
    int t = (threadIdx.x >= (unsigned)off) ? sm[threadIdx.x - off] : 0;
    __syncthreads();
    sm[threadIdx.x] += t;
    __syncthreads();
  }
  if (i < N_NODES) excl[r * N_NODES + i] = sm[threadIdx.x] - v;
  if (threadIdx.x == 1023) part[r * NCHUNK + blockIdx.x] = sm[1023];
}

// scan phase 2: exclusive scan of the <=98 chunk totals per relation
__global__ void scan2_kernel(int* __restrict__ part) {
  int r = blockIdx.x;
  int* p = part + r * NCHUNK;
  __shared__ int sm[128];
  int tid = threadIdx.x;
  int v = (tid < NCHUNK) ? p[tid] : 0;
  sm[tid] = v;
  __syncthreads();
  for (int off = 1; off < 128; off <<= 1) {
    int t = (tid >= off) ? sm[tid - off] : 0;
    __syncthreads();
    sm[tid] += t;
    __syncthreads();
  }
  if (tid < NCHUNK) p[tid] = sm[tid] - v;
}

// scan phase 3: row_off = excl + scanned chunk base; row_off[N] = E
__global__ void scan3_kernel(const int* __restrict__ excl, const int* __restrict__ part,
                             int* __restrict__ row_off) {
  int r = blockIdx.y;
  int i = blockIdx.x * 1024 + threadIdx.x;
  if (i < N_NODES) row_off[r * (N_NODES + 1) + i] = excl[r * N_NODES + i] + part[r * NCHUNK + (i >> 10)];
  if (i == N_NODES) row_off[r * (N_NODES + 1) + N_NODES] = N_EDGE;
}

// atomic-free scatter into sorted edge slots
__global__ void scatter_kernel(const int* __restrict__ src, const int* __restrict__ dst,
                               const int* __restrict__ pos,
                               const float* __restrict__ inv_out, const float* __restrict__ inv_in,
                               const int* __restrict__ row_off, float2* __restrict__ sorted_sc) {
  int tid = blockIdx.x * blockDim.x + threadIdx.x;
  if (tid >= N_REL * N_EDGE) return;
  int r = tid / N_EDGE;
  int s = src[tid], d = dst[tid];
  int o = row_off[r * (N_NODES + 1) + d] + pos[tid];
  float coef = inv_out[r * N_NODES + s] * inv_in[r * N_NODES + d];
  sorted_sc[(size_t)r * N_EDGE + o] = make_float2(__int_as_float(s), coef);
}

// ---------------- per-layer kernels ----------------

// Gather-first: agg[n][r*128 + c] = sum_{e in CSR_r(n)} coef_e * h[src_e][c]
// Half-wave per edge: one wave-load (64 lanes x float4 = 1KB) fetches TWO 512B rows.
__launch_bounds__(256)
__global__ void agg_kernel(const float* __restrict__ h, const float2* __restrict__ sc,
                           const int* __restrict__ row_off, float* __restrict__ agg) {
  int r    = blockIdx.y;
  int node = blockIdx.x * 4 + ((int)threadIdx.x >> 6);
  int lane = (int)threadIdx.x & 63;
  int half = lane >> 5;          // which edge of the pair
  int l    = lane & 31;          // float4 slot within the row
  if (node >= N_NODES) return;
  const int* ro = row_off + r * (N_NODES + 1);
  int beg = ro[node], end = ro[node + 1];
  const float2* scp = sc + (size_t)r * N_EDGE;
  const float4* hp  = (const float4*)h;    // row = 32 float4
  float4 acc = make_float4(0.f, 0.f, 0.f, 0.f);
  int e = beg + half;
  for (; e + 6 < end; e += 8) {            // 8 edges per wave-iteration in flight
    float2 q0 = scp[e], q1 = scp[e + 2], q2 = scp[e + 4], q3 = scp[e + 6];
    float4 v0 = hp[(size_t)__float_as_int(q0.x) * 32 + l];
    float4 v1 = hp[(size_t)__float_as_int(q1.x) * 32 + l];
    float4 v2 = hp[(size_t)__float_as_int(q2.x) * 32 + l];
    float4 v3 = hp[(size_t)__float_as_int(q3.x) * 32 + l];
    acc.x = fmaf(q0.y, v0.x, acc.x); acc.y = fmaf(q0.y, v0.y, acc.y);
    acc.z = fmaf(q0.y, v0.z, acc.z); acc.w = fmaf(q0.y, v0.w, acc.w);
    acc.x = fmaf(q1.y, v1.x, acc.x); acc.y = fmaf(q1.y, v1.y, acc.y);
    acc.z = fmaf(q1.y, v1.z, acc.z); acc.w = fmaf(q1.y, v1.w, acc.w);
    acc.x = fmaf(q2.y, v2.x, acc.x); acc.y = fmaf(q2.y, v2.y, acc.y);
    acc.z = fmaf(q2.y, v2.z, acc.z); acc.w = fmaf(q2.y, v2.w, acc.w);
    acc.x = fmaf(q3.y, v3.x, acc.x); acc.y = fmaf(q3.y, v3.y, acc.y);
    acc.z = fmaf(q3.y, v3.z, acc.z); acc.w = fmaf(q3.y, v3.w, acc.w);
  }
  for (; e < end; e += 2) {
    float2 q = scp[e];
    float4 v = hp[(size_t)__float_as_int(q.x) * 32 + l];
    acc.x = fmaf(q.y, v.x, acc.x); acc.y = fmaf(q.y, v.y, acc.y);
    acc.z = fmaf(q.y, v.z, acc.z); acc.w = fmaf(q.y, v.w, acc.w);
  }
  // combine the two half-wave partial sums (same columns, disjoint edges)
  acc.x += __shfl_xor(acc.x, 32);
  acc.y += __shfl_xor(acc.y, 32);
  acc.z += __shfl_xor(acc.z, 32);
  acc.w += __shfl_xor(acc.w, 32);
  if (half == 0)
    ((float4*)(agg + (size_t)node * 384 + r * 128))[l] = acc;
}

// out[n][:] = relu?( agg[n][0:384] @ Wcat[384][DO] + sum_r b[r][:] )
template<int DO>
__launch_bounds__(256)
__global__ void gemm_kernel(const float* __restrict__ A, const float* __restrict__ W,
                            const float* __restrict__ b, float* __restrict__ out, int apply_relu) {
  constexpr int TN = DO / 16;      // cols per thread (8 or 4)
  constexpr int K  = 384;
  int m0 = blockIdx.x * 128;
  int tid = threadIdx.x;
  int tx = tid & 15;               // col group
  int ty = tid >> 4;               // row group
  __shared__ float As[128][17];
  __shared__ float Bs[16][DO];
  float acc[8][TN];
  #pragma unroll
  for (int i = 0; i < 8; i++)
    #pragma unroll
    for (int j = 0; j < TN; j++) acc[i][j] = 0.f;

  for (int k0 = 0; k0 < K; k0 += 16) {
    // A tile: float4 global loads, scalar LDS writes (As row pad 17 breaks conflicts)
    #pragma unroll
    for (int idx = tid; idx < 128 * 4; idx += 256) {
      int row = idx >> 2, kq = idx & 3;
      float4 v = make_float4(0.f, 0.f, 0.f, 0.f);
      if (m0 + row < N_NODES) v = *(const float4*)(A + (size_t)(m0 + row) * K + k0 + kq * 4);
      As[row][kq * 4 + 0] = v.x; As[row][kq * 4 + 1] = v.y;
      As[row][kq * 4 + 2] = v.z; As[row][kq * 4 + 3] = v.w;
    }
    // B tile: float4 both sides (Bs rows are 16B-aligned)
    #pragma unroll
    for (int idx = tid; idx < 16 * DO / 4; idx += 256) {
      int kk = idx / (DO / 4), cq = idx % (DO / 4);
      float4 v = *(const float4*)(W + (size_t)(k0 + kk) * DO + cq * 4);
      *(float4*)(&Bs[kk][cq * 4]) = v;
    }
    __syncthreads();
    #pragma unroll
    for (int kk = 0; kk < 16; kk++) {
      float a[8], bv[TN];
      #pragma unroll
      for (int i = 0; i < 8; i++) a[i] = As[ty * 8 + i][kk];
      #pragma unroll
      for (int j = 0; j < TN; j++) bv[j] = Bs[kk][tx * TN + j];
      #pragma unroll
      for (int i = 0; i < 8; i++)
        #pragma unroll
        for (int j = 0; j < TN; j++) acc[i][j] = fmaf(a[i], bv[j], acc[i][j]);
    }
    __syncthreads();
  }
  float bias[TN];
  #pragma unroll
  for (int j = 0; j < TN; j++) {
    int c = tx * TN + j;
    bias[j] = b[0 * DO + c] + b[1 * DO + c] + b[2 * DO + c];
  }
  #pragma unroll
  for (int i = 0; i < 8; i++) {
    int row = m0 + ty * 8 + i;
    if (row < N_NODES) {
      float* yp = out + (size_t)row * DO + tx * TN;
      #pragma unroll
      for (int j = 0; j < TN; j += 4) {
        float4 v = make_float4(acc[i][j] + bias[j], acc[i][j+1] + bias[j+1],
                               acc[i][j+2] + bias[j+2], acc[i][j+3] + bias[j+3]);
        if (apply_relu) {
          v.x = fmaxf(v.x, 0.f); v.y = fmaxf(v.y, 0.f);
          v.z = fmaxf(v.z, 0.f); v.w = fmaxf(v.w, 0.f);
        }
        *(float4*)(yp + j) = v;
      }
    }
  }
}

// ---------------- launch ----------------

extern "C" void kernel_launch(void* const* d_in, const int* in_sizes, int n_in,
                              void* d_out, int out_size, void* d_ws, size_t ws_size,
                              hipStream_t stream) {
  const float* x   = (const float*)d_in[0];
  const int*   src = (const int*)d_in[1];
  const int*   dst = (const int*)d_in[2];
  const float* Wl[6]; const float* bl[6];
  for (int i = 0; i < 6; i++) { Wl[i] = (const float*)d_in[3 + 2*i]; bl[i] = (const float*)d_in[4 + 2*i]; }

  // Workspace budget is 256 MiB — total below is ~250.4 MB.
  // pos/excl are preprocessing-only and alias aggbuf (first written later, in agg_kernel).
  char* ws = (char*)d_ws;
  size_t off = 0;
  auto take = [&](size_t bytes) -> char* {
    char* p = ws + off;
    off = (off + bytes + 255) & ~(size_t)255;
    return p;
  };
  float*  h       = (float*)take((size_t)N_NODES * 128 * 4);
  float*  aggbuf  = (float*)take((size_t)N_NODES * 384 * 4);
  int*    deg     = (int*)  take((size_t)2 * N_REL * N_NODES * 4);   // deg_out | deg_in
  int*    deg_out = deg;
  int*    deg_in  = deg + N_REL * N_NODES;
  float*  inv_out = (float*)take((size_t)N_REL * N_NODES * 4);
  float*  inv_in  = (float*)take((size_t)N_REL * N_NODES * 4);
  int*    row_off = (int*)  take((size_t)N_REL * (N_NODES + 1) * 4);
  int*    part    = (int*)  take((size_t)N_REL * NCHUNK * 4);
  float2* s_sc    = (float2*)take((size_t)N_REL * N_EDGE * 8);
  // aliases into aggbuf (dead before first agg_kernel write):
  int*    pos     = (int*)aggbuf;                          // 19.2 MB
  int*    excl    = (int*)aggbuf + (size_t)N_REL * N_EDGE; // 1.2 MB, right after pos
  (void)ws_size; (void)in_sizes; (void)n_in; (void)out_size;

  hipMemsetAsync(deg, 0, (size_t)2 * N_REL * N_NODES * 4, stream);

  const int eblocks = (N_REL * N_EDGE + 255) / 256;
  const int nblocks = (N_REL * N_NODES + 255) / 256;
  p1_kernel<<<eblocks, 256, 0, stream>>>(src, dst, deg_out, deg_in, pos);
  inv_kernel<<<nblocks, 256, 0, stream>>>(deg_out, deg_in, inv_out, inv_in);
  scan1_kernel<<<dim3(NCHUNK, 3), 1024, 0, stream>>>(deg_in, excl, part);
  scan2_kernel<<<3, 128, 0, stream>>>(part);
  scan3_kernel<<<dim3(NCHUNK + 1, 3), 1024, 0, stream>>>(excl, part, row_off);
  scatter_kernel<<<eblocks, 256, 0, stream>>>(src, dst, pos, inv_out, inv_in, row_off, s_sc);

  const int mtiles = (N_NODES + 127) / 128;
  const int agg_blocks = (N_NODES + 3) / 4;
  const float* h_in = x;
  for (int L = 0; L < 6; L++) {
    agg_kernel<<<dim3(agg_blocks, 3), 256, 0, stream>>>(h_in, s_sc, row_off, aggbuf);
    if (L < 5) {
      gemm_kernel<128><<<mtiles, 256, 0, stream>>>(aggbuf, Wl[L], bl[L], h, 1);
      h_in = h;
    } else {
      gemm_kernel<64><<<mtiles, 256, 0, stream>>>(aggbuf, Wl[L], bl[L], (float*)d_out, 0);
    }
  }
}

// Round 6
// 3356.678 us; speedup vs baseline: 1.2642x; 1.0420x over previous
//
#include <hip/hip_runtime.h>
#include <hip/hip_bf16.h>

constexpr int N_NODES = 100000;
constexpr int N_REL   = 3;
constexpr int N_EDGE  = 1600000;
constexpr int NCHUNK  = (N_NODES + 1023) / 1024;   // 98

typedef __attribute__((ext_vector_type(8))) short short8;
typedef __attribute__((ext_vector_type(4))) float f32x4;

__device__ inline ushort f2bf(float x) {            // round-to-nearest-even bf16
  unsigned u = __float_as_uint(x);
  unsigned r = u + 0x7FFFu + ((u >> 16) & 1u);
  return (ushort)(r >> 16);
}
__device__ inline float bf2f(ushort h) { return __uint_as_float(((unsigned)h) << 16); }

// ---------------- graph preprocessing ----------------

__global__ void p1_kernel(const int* __restrict__ src, const int* __restrict__ dst,
                          int* __restrict__ deg_out, int* __restrict__ deg_in,
                          int* __restrict__ pos) {
  int tid = blockIdx.x * blockDim.x + threadIdx.x;
  if (tid >= N_REL * N_EDGE) return;
  int r = tid / N_EDGE;
  pos[tid] = atomicAdd(&deg_in[r * N_NODES + dst[tid]], 1);
  atomicAdd(&deg_out[r * N_NODES + src[tid]], 1);
}

__global__ void inv_kernel(const int* __restrict__ deg_out, const int* __restrict__ deg_in,
                           float* __restrict__ inv_out, float* __restrict__ inv_in) {
  int i = blockIdx.x * blockDim.x + threadIdx.x;
  if (i >= N_REL * N_NODES) return;
  inv_out[i] = rsqrtf(fmaxf((float)deg_out[i], 1.0f));
  inv_in[i]  = rsqrtf(fmaxf((float)deg_in[i],  1.0f));
}

__global__ void scan1_kernel(const int* __restrict__ deg_in, int* __restrict__ excl,
                             int* __restrict__ part) {
  int r = blockIdx.y;
  int i = blockIdx.x * 1024 + threadIdx.x;
  int v = (i < N_NODES) ? deg_in[r * N_NODES + i] : 0;
  __shared__ int sm[1024];
  sm[threadIdx.x] = v;
  __syncthreads();
  for (int off = 1; off < 1024; off <<= 1) {
    int t = (threadIdx.x >= (unsigned)off) ? sm[threadIdx.x - off] : 0;
    __syncthreads();
    sm[threadIdx.x] += t;
    __syncthreads();
  }
  if (i < N_NODES) excl[r * N_NODES + i] = sm[threadIdx.x] - v;
  if (threadIdx.x == 1023) part[r * NCHUNK + blockIdx.x] = sm[1023];
}

__global__ void scan2_kernel(int* __restrict__ part) {
  int r = blockIdx.x;
  int* p = part + r * NCHUNK;
  __shared__ int sm[128];
  int tid = threadIdx.x;
  int v = (tid < NCHUNK) ? p[tid] : 0;
  sm[tid] = v;
  __syncthreads();
  for (int off = 1; off < 128; off <<= 1) {
    int t = (tid >= off) ? sm[tid - off] : 0;
    __syncthreads();
    sm[tid] += t;
    __syncthreads();
  }
  if (tid < NCHUNK) p[tid] = sm[tid] - v;
}

__global__ void scan3_kernel(const int* __restrict__ excl, const int* __restrict__ part,
                             int* __restrict__ row_off) {
  int r = blockIdx.y;
  int i = blockIdx.x * 1024 + threadIdx.x;
  if (i < N_NODES) row_off[r * (N_NODES + 1) + i] = excl[r * N_NODES + i] + part[r * NCHUNK + (i >> 10)];
  if (i == N_NODES) row_off[r * (N_NODES + 1) + N_NODES] = N_EDGE;
}

__global__ void scatter_kernel(const int* __restrict__ src, const int* __restrict__ dst,
                               const int* __restrict__ pos,
                               const float* __restrict__ inv_out, const float* __restrict__ inv_in,
                               const int* __restrict__ row_off, float2* __restrict__ sorted_sc) {
  int tid = blockIdx.x * blockDim.x + threadIdx.x;
  if (tid >= N_REL * N_EDGE) return;
  int r = tid / N_EDGE;
  int s = src[tid], d = dst[tid];
  int o = row_off[r * (N_NODES + 1) + d] + pos[tid];
  float coef = inv_out[r * N_NODES + s] * inv_in[r * N_NODES + d];
  sorted_sc[(size_t)r * N_EDGE + o] = make_float2(__int_as_float(s), coef);
}

// ---------------- per-layer kernels ----------------

// Gather-first: agg[n][r*128+c] = sum coef_e * h[src_e][c].
// Half-wave per edge, 16 edges per iteration (8 gathers in flight per half).
__launch_bounds__(256)
__global__ void agg_kernel(const float* __restrict__ h, const float2* __restrict__ sc,
                           const int* __restrict__ row_off, float* __restrict__ agg) {
  int r    = blockIdx.y;
  int node = blockIdx.x * 4 + ((int)threadIdx.x >> 6);
  int lane = (int)threadIdx.x & 63;
  int half = lane >> 5;
  int l    = lane & 31;
  if (node >= N_NODES) return;
  const int* ro = row_off + r * (N_NODES + 1);
  int beg = ro[node], end = ro[node + 1];
  const float2* scp = sc + (size_t)r * N_EDGE;
  const float4* hp  = (const float4*)h;    // row = 32 float4
  float4 acc = make_float4(0.f, 0.f, 0.f, 0.f);
  int e = beg;
  for (; e + 16 <= end; e += 16) {
    int base = e + half * 8;
    float2 q[8];
    #pragma unroll
    for (int j = 0; j < 8; j++) q[j] = scp[base + j];
    float4 v[8];
    #pragma unroll
    for (int j = 0; j < 8; j++) v[j] = hp[(size_t)__float_as_int(q[j].x) * 32 + l];
    #pragma unroll
    for (int j = 0; j < 8; j++) {
      acc.x = fmaf(q[j].y, v[j].x, acc.x);
      acc.y = fmaf(q[j].y, v[j].y, acc.y);
      acc.z = fmaf(q[j].y, v[j].z, acc.z);
      acc.w = fmaf(q[j].y, v[j].w, acc.w);
    }
  }
  for (int e2 = e + half; e2 < end; e2 += 2) {
    float2 q = scp[e2];
    float4 v = hp[(size_t)__float_as_int(q.x) * 32 + l];
    acc.x = fmaf(q.y, v.x, acc.x); acc.y = fmaf(q.y, v.y, acc.y);
    acc.z = fmaf(q.y, v.z, acc.z); acc.w = fmaf(q.y, v.w, acc.w);
  }
  acc.x += __shfl_xor(acc.x, 32);
  acc.y += __shfl_xor(acc.y, 32);
  acc.z += __shfl_xor(acc.z, 32);
  acc.w += __shfl_xor(acc.w, 32);
  if (half == 0)
    ((float4*)(agg + (size_t)node * 384 + r * 128))[l] = acc;
}

// bf16x3 split MFMA GEMM: out = relu?( A[128-tile][384] @ W[384][DO] + sum_r b )
// A,W fp32 -> (hi,lo) bf16 pairs; A*W ~= Ah*Wh + Ah*Wl + Al*Wh (rel err ~3e-5).
// Tile M=128 x N=DO; 4 waves, wave w = rows [32w,32w+32): 2 row-tiles x (DO/16) col-tiles
// of v_mfma_f32_16x16x32_bf16. LDS rows padded to 40 ushorts (80B -> 2-way conflicts, free).
template<int DO>
__launch_bounds__(256, 2)
__global__ void gemm_kernel(const float* __restrict__ A, const float* __restrict__ W,
                            const float* __restrict__ b, float* __restrict__ out, int apply_relu) {
  constexpr int K   = 384;
  constexpr int KC  = 32;
  constexpr int NCT = DO / 16;
  constexpr int LDA = 40;
  __shared__ ushort As_hi[128 * LDA], As_lo[128 * LDA];
  __shared__ ushort Bs_hi[DO * LDA],  Bs_lo[DO * LDA];
  int tid  = threadIdx.x;
  int wave = tid >> 6, lane = tid & 63;
  int quad = lane >> 4, m16 = lane & 15;
  int m0 = blockIdx.x * 128;

  f32x4 acc[2][NCT];
  #pragma unroll
  for (int rt = 0; rt < 2; rt++)
    #pragma unroll
    for (int ct = 0; ct < NCT; ct++) acc[rt][ct] = (f32x4){0.f, 0.f, 0.f, 0.f};

  for (int kc = 0; kc < K; kc += KC) {
    __syncthreads();
    // stage A tile: 128 rows x 32 k (fp32 -> hi/lo bf16)
    #pragma unroll
    for (int q = 0; q < 4; q++) {
      int idx = tid * 4 + q;          // 0..1023
      int row = idx >> 3;
      int kp  = (idx & 7) * 4;
      float4 v = make_float4(0.f, 0.f, 0.f, 0.f);
      if (m0 + row < N_NODES) v = *(const float4*)(A + (size_t)(m0 + row) * K + kc + kp);
      float xv[4] = {v.x, v.y, v.z, v.w};
      ushort hh[4], ll[4];
      #pragma unroll
      for (int j = 0; j < 4; j++) {
        hh[j] = f2bf(xv[j]);
        ll[j] = f2bf(xv[j] - bf2f(hh[j]));
      }
      *(ushort4*)&As_hi[row * LDA + kp] = make_ushort4(hh[0], hh[1], hh[2], hh[3]);
      *(ushort4*)&As_lo[row * LDA + kp] = make_ushort4(ll[0], ll[1], ll[2], ll[3]);
    }
    // stage B tile transposed: Bs[n][k], k-contiguous
    #pragma unroll
    for (int q = 0; q < DO / 32; q++) {
      int idx = q * 256 + tid;        // over 8*DO float4 loads
      int kk = idx / (DO / 4);
      int cq = idx % (DO / 4);
      float4 v = *(const float4*)(W + (size_t)(kc + kk) * DO + cq * 4);
      float xv[4] = {v.x, v.y, v.z, v.w};
      #pragma unroll
      for (int j = 0; j < 4; j++) {
        int c = cq * 4 + j;
        ushort hh = f2bf(xv[j]);
        Bs_hi[c * LDA + kk] = hh;
        Bs_lo[c * LDA + kk] = f2bf(xv[j] - bf2f(hh));
      }
    }
    __syncthreads();

    short8 ah[2], al[2];
    #pragma unroll
    for (int rt = 0; rt < 2; rt++) {
      int m = wave * 32 + rt * 16 + m16;
      ah[rt] = *(const short8*)&As_hi[m * LDA + quad * 8];
      al[rt] = *(const short8*)&As_lo[m * LDA + quad * 8];
    }
    #pragma unroll
    for (int ct = 0; ct < NCT; ct++) {
      int n = ct * 16 + m16;
      short8 bh = *(const short8*)&Bs_hi[n * LDA + quad * 8];
      short8 bl = *(const short8*)&Bs_lo[n * LDA + quad * 8];
      #pragma unroll
      for (int rt = 0; rt < 2; rt++) {
        acc[rt][ct] = __builtin_amdgcn_mfma_f32_16x16x32_bf16(ah[rt], bh, acc[rt][ct], 0, 0, 0);
        acc[rt][ct] = __builtin_amdgcn_mfma_f32_16x16x32_bf16(ah[rt], bl, acc[rt][ct], 0, 0, 0);
        acc[rt][ct] = __builtin_amdgcn_mfma_f32_16x16x32_bf16(al[rt], bh, acc[rt][ct], 0, 0, 0);
      }
    }
  }
  // epilogue: C/D layout col=lane&15, row=quad*4+reg
  #pragma unroll
  for (int ct = 0; ct < NCT; ct++) {
    int col = ct * 16 + m16;
    float bs = b[col] + b[DO + col] + b[2 * DO + col];
    #pragma unroll
    for (int rt = 0; rt < 2; rt++) {
      #pragma unroll
      for (int v = 0; v < 4; v++) {
        int row = m0 + wave * 32 + rt * 16 + quad * 4 + v;
        if (row < N_NODES) {
          float o = acc[rt][ct][v] + bs;
          if (apply_relu) o = fmaxf(o, 0.f);
          out[(size_t)row * DO + col] = o;
        }
      }
    }
  }
}

// ---------------- launch ----------------

extern "C" void kernel_launch(void* const* d_in, const int* in_sizes, int n_in,
                              void* d_out, int out_size, void* d_ws, size_t ws_size,
                              hipStream_t stream) {
  const float* x   = (const float*)d_in[0];
  const int*   src = (const int*)d_in[1];
  const int*   dst = (const int*)d_in[2];
  const float* Wl[6]; const float* bl[6];
  for (int i = 0; i < 6; i++) { Wl[i] = (const float*)d_in[3 + 2*i]; bl[i] = (const float*)d_in[4 + 2*i]; }

  // Workspace ~250.4 MB of the 256 MiB budget.
  // pos/excl alias aggbuf (dead before first agg_kernel write).
  char* ws = (char*)d_ws;
  size_t off = 0;
  auto take = [&](size_t bytes) -> char* {
    char* p = ws + off;
    off = (off + bytes + 255) & ~(size_t)255;
    return p;
  };
  float*  h       = (float*)take((size_t)N_NODES * 128 * 4);
  float*  aggbuf  = (float*)take((size_t)N_NODES * 384 * 4);
  int*    deg     = (int*)  take((size_t)2 * N_REL * N_NODES * 4);
  int*    deg_out = deg;
  int*    deg_in  = deg + N_REL * N_NODES;
  float*  inv_out = (float*)take((size_t)N_REL * N_NODES * 4);
  float*  inv_in  = (float*)take((size_t)N_REL * N_NODES * 4);
  int*    row_off = (int*)  take((size_t)N_REL * (N_NODES + 1) * 4);
  int*    part    = (int*)  take((size_t)N_REL * NCHUNK * 4);
  float2* s_sc    = (float2*)take((size_t)N_REL * N_EDGE * 8);
  int*    pos     = (int*)aggbuf;
  int*    excl    = (int*)aggbuf + (size_t)N_REL * N_EDGE;
  (void)ws_size; (void)in_sizes; (void)n_in; (void)out_size;

  hipMemsetAsync(deg, 0, (size_t)2 * N_REL * N_NODES * 4, stream);

  const int eblocks = (N_REL * N_EDGE + 255) / 256;
  const int nblocks = (N_REL * N_NODES + 255) / 256;
  p1_kernel<<<eblocks, 256, 0, stream>>>(src, dst, deg_out, deg_in, pos);
  inv_kernel<<<nblocks, 256, 0, stream>>>(deg_out, deg_in, inv_out, inv_in);
  scan1_kernel<<<dim3(NCHUNK, 3), 1024, 0, stream>>>(deg_in, excl, part);
  scan2_kernel<<<3, 128, 0, stream>>>(part);
  scan3_kernel<<<dim3(NCHUNK + 1, 3), 1024, 0, stream>>>(excl, part, row_off);
  scatter_kernel<<<eblocks, 256, 0, stream>>>(src, dst, pos, inv_out, inv_in, row_off, s_sc);

  const int mtiles = (N_NODES + 127) / 128;
  const int agg_blocks = (N_NODES + 3) / 4;
  const float* h_in = x;
  for (int L = 0; L < 6; L++) {
    agg_kernel<<<dim3(agg_blocks, 3), 256, 0, stream>>>(h_in, s_sc, row_off, aggbuf);
    if (L < 5) {
      gemm_kernel<128><<<mtiles, 256, 0, stream>>>(aggbuf, Wl[L], bl[L], h, 1);
      h_in = h;
    } else {
      gemm_kernel<64><<<mtiles, 256, 0, stream>>>(aggbuf, Wl[L], bl[L], (float*)d_out, 0);
    }
  }
}

// Round 7
// 3100.641 us; speedup vs baseline: 1.3686x; 1.0826x over previous
//
#include <hip/hip_runtime.h>
#include <hip/hip_bf16.h>

constexpr int N_NODES = 100000;
constexpr int N_REL   = 3;
constexpr int N_EDGE  = 1600000;
constexpr int NCHUNK  = (N_NODES + 1023) / 1024;   // 98

typedef __attribute__((ext_vector_type(8))) short short8;
typedef __attribute__((ext_vector_type(4))) float f32x4;

__device__ inline ushort f2bf(float x) {            // round-to-nearest-even bf16
  unsigned u = __float_as_uint(x);
  unsigned r = u + 0x7FFFu + ((u >> 16) & 1u);
  return (ushort)(r >> 16);
}
__device__ inline float bf2f(ushort h) { return __uint_as_float(((unsigned)h) << 16); }

// ---------------- graph preprocessing ----------------

__global__ void p1_kernel(const int* __restrict__ src, const int* __restrict__ dst,
                          int* __restrict__ deg_out, int* __restrict__ deg_in,
                          int* __restrict__ pos) {
  int tid = blockIdx.x * blockDim.x + threadIdx.x;
  if (tid >= N_REL * N_EDGE) return;
  int r = tid / N_EDGE;
  pos[tid] = atomicAdd(&deg_in[r * N_NODES + dst[tid]], 1);
  atomicAdd(&deg_out[r * N_NODES + src[tid]], 1);
}

__global__ void inv_kernel(const int* __restrict__ deg_out, const int* __restrict__ deg_in,
                           float* __restrict__ inv_out, float* __restrict__ inv_in) {
  int i = blockIdx.x * blockDim.x + threadIdx.x;
  if (i >= N_REL * N_NODES) return;
  inv_out[i] = rsqrtf(fmaxf((float)deg_out[i], 1.0f));
  inv_in[i]  = rsqrtf(fmaxf((float)deg_in[i],  1.0f));
}

__global__ void scan1_kernel(const int* __restrict__ deg_in, int* __restrict__ excl,
                             int* __restrict__ part) {
  int r = blockIdx.y;
  int i = blockIdx.x * 1024 + threadIdx.x;
  int v = (i < N_NODES) ? deg_in[r * N_NODES + i] : 0;
  __shared__ int sm[1024];
  sm[threadIdx.x] = v;
  __syncthreads();
  for (int off = 1; off < 1024; off <<= 1) {
    int t = (threadIdx.x >= (unsigned)off) ? sm[threadIdx.x - off] : 0;
    __syncthreads();
    sm[threadIdx.x] += t;
    __syncthreads();
  }
  if (i < N_NODES) excl[r * N_NODES + i] = sm[threadIdx.x] - v;
  if (threadIdx.x == 1023) part[r * NCHUNK + blockIdx.x] = sm[1023];
}

__global__ void scan2_kernel(int* __restrict__ part) {
  int r = blockIdx.x;
  int* p = part + r * NCHUNK;
  __shared__ int sm[128];
  int tid = threadIdx.x;
  int v = (tid < NCHUNK) ? p[tid] : 0;
  sm[tid] = v;
  __syncthreads();
  for (int off = 1; off < 128; off <<= 1) {
    int t = (tid >= off) ? sm[tid - off] : 0;
    __syncthreads();
    sm[tid] += t;
    __syncthreads();
  }
  if (tid < NCHUNK) p[tid] = sm[tid] - v;
}

__global__ void scan3_kernel(const int* __restrict__ excl, const int* __restrict__ part,
                             int* __restrict__ row_off) {
  int r = blockIdx.y;
  int i = blockIdx.x * 1024 + threadIdx.x;
  if (i < N_NODES) row_off[r * (N_NODES + 1) + i] = excl[r * N_NODES + i] + part[r * NCHUNK + (i >> 10)];
  if (i == N_NODES) row_off[r * (N_NODES + 1) + N_NODES] = N_EDGE;
}

__global__ void scatter_kernel(const int* __restrict__ src, const int* __restrict__ dst,
                               const int* __restrict__ pos,
                               const float* __restrict__ inv_out, const float* __restrict__ inv_in,
                               const int* __restrict__ row_off, float2* __restrict__ sorted_sc) {
  int tid = blockIdx.x * blockDim.x + threadIdx.x;
  if (tid >= N_REL * N_EDGE) return;
  int r = tid / N_EDGE;
  int s = src[tid], d = dst[tid];
  int o = row_off[r * (N_NODES + 1) + d] + pos[tid];
  float coef = inv_out[r * N_NODES + s] * inv_in[r * N_NODES + d];
  sorted_sc[(size_t)r * N_EDGE + o] = make_float2(__int_as_float(s), coef);
}

// per-layer weight preconvert: W[k][c] fp32 -> transposed hi/lo bf16 planes Wt[c][k]
__global__ void convw_kernel(const float* __restrict__ W, ushort* __restrict__ Wh,
                             ushort* __restrict__ Wl, int DOv) {
  int idx = blockIdx.x * 256 + threadIdx.x;
  if (idx >= 384 * DOv) return;
  int k = idx / DOv, c = idx % DOv;
  float v = W[idx];
  ushort hh = f2bf(v);
  Wh[c * 384 + k] = hh;
  Wl[c * 384 + k] = f2bf(v - bf2f(hh));
}

// ---------------- per-layer kernels ----------------

// Gather-first: acc[n][r*128+c] = sum coef_e * h[src_e][c] (fp32 math),
// emitted as bf16 hi/lo planes so the GEMM stages without any conversion.
__launch_bounds__(256)
__global__ void agg_kernel(const float* __restrict__ h, const float2* __restrict__ sc,
                           const int* __restrict__ row_off,
                           ushort* __restrict__ agg_hi, ushort* __restrict__ agg_lo) {
  int r    = blockIdx.y;
  int node = blockIdx.x * 4 + ((int)threadIdx.x >> 6);
  int lane = (int)threadIdx.x & 63;
  int half = lane >> 5;
  int l    = lane & 31;
  if (node >= N_NODES) return;
  const int* ro = row_off + r * (N_NODES + 1);
  int beg = ro[node], end = ro[node + 1];
  const float2* scp = sc + (size_t)r * N_EDGE;
  const float4* hp  = (const float4*)h;    // row = 32 float4
  float4 acc = make_float4(0.f, 0.f, 0.f, 0.f);
  int e = beg;
  for (; e + 16 <= end; e += 16) {
    int base = e + half * 8;
    float2 q[8];
    #pragma unroll
    for (int j = 0; j < 8; j++) q[j] = scp[base + j];
    float4 v[8];
    #pragma unroll
    for (int j = 0; j < 8; j++) v[j] = hp[(size_t)__float_as_int(q[j].x) * 32 + l];
    #pragma unroll
    for (int j = 0; j < 8; j++) {
      acc.x = fmaf(q[j].y, v[j].x, acc.x);
      acc.y = fmaf(q[j].y, v[j].y, acc.y);
      acc.z = fmaf(q[j].y, v[j].z, acc.z);
      acc.w = fmaf(q[j].y, v[j].w, acc.w);
    }
  }
  for (int e2 = e + half; e2 < end; e2 += 2) {
    float2 q = scp[e2];
    float4 v = hp[(size_t)__float_as_int(q.x) * 32 + l];
    acc.x = fmaf(q.y, v.x, acc.x); acc.y = fmaf(q.y, v.y, acc.y);
    acc.z = fmaf(q.y, v.z, acc.z); acc.w = fmaf(q.y, v.w, acc.w);
  }
  acc.x += __shfl_xor(acc.x, 32);
  acc.y += __shfl_xor(acc.y, 32);
  acc.z += __shfl_xor(acc.z, 32);
  acc.w += __shfl_xor(acc.w, 32);
  if (half == 0) {
    ushort4 hi, lo;
    hi.x = f2bf(acc.x); lo.x = f2bf(acc.x - bf2f(hi.x));
    hi.y = f2bf(acc.y); lo.y = f2bf(acc.y - bf2f(hi.y));
    hi.z = f2bf(acc.z); lo.z = f2bf(acc.z - bf2f(hi.z));
    hi.w = f2bf(acc.w); lo.w = f2bf(acc.w - bf2f(hi.w));
    size_t base = (size_t)node * 384 + r * 128 + l * 4;
    *(ushort4*)(agg_hi + base) = hi;
    *(ushort4*)(agg_lo + base) = lo;
  }
}

// bf16x3 split MFMA GEMM, conversion-free staging:
// out = relu?( A(hi+lo)[128-tile][384] @ W(hi+lo)[384][DO] + sum_r b )
// A*W ~= Ah*Wh + Ah*Wl + Al*Wh. LDS rows padded to 40 ushorts.
template<int DO>
__launch_bounds__(256)
__global__ void gemm_kernel(const ushort* __restrict__ Ah, const ushort* __restrict__ Al,
                            const ushort* __restrict__ Wh, const ushort* __restrict__ Wl,
                            const float* __restrict__ b, float* __restrict__ out, int apply_relu) {
  constexpr int K   = 384;
  constexpr int KC  = 32;
  constexpr int NCT = DO / 16;
  constexpr int LDA = 40;
  __shared__ ushort As_hi[128 * LDA], As_lo[128 * LDA];
  __shared__ ushort Bs_hi[DO * LDA],  Bs_lo[DO * LDA];
  int tid  = threadIdx.x;
  int wave = tid >> 6, lane = tid & 63;
  int quad = lane >> 4, m16 = lane & 15;
  int m0 = blockIdx.x * 128;

  f32x4 acc[2][NCT];
  #pragma unroll
  for (int rt = 0; rt < 2; rt++)
    #pragma unroll
    for (int ct = 0; ct < NCT; ct++) acc[rt][ct] = (f32x4){0.f, 0.f, 0.f, 0.f};

  for (int kc = 0; kc < K; kc += KC) {
    __syncthreads();
    // A tile: 128 rows x 32 k, two planes, pure 16B copies
    #pragma unroll
    for (int it = 0; it < 2; it++) {
      int idx = it * 256 + tid;            // 0..511
      int row = idx >> 2, kq = (idx & 3) * 8;
      uint4 vh = make_uint4(0u, 0u, 0u, 0u), vl = make_uint4(0u, 0u, 0u, 0u);
      if (m0 + row < N_NODES) {
        vh = *(const uint4*)(Ah + (size_t)(m0 + row) * K + kc + kq);
        vl = *(const uint4*)(Al + (size_t)(m0 + row) * K + kc + kq);
      }
      *(uint4*)&As_hi[row * LDA + kq] = vh;
      *(uint4*)&As_lo[row * LDA + kq] = vl;
    }
    // B tile from pretransposed W: DO rows x 32 k, two planes
    #pragma unroll
    for (int it = 0; it < DO / 64; it++) {
      int idx = it * 256 + tid;            // 0..DO*4-1
      int n = idx >> 2, kq = (idx & 3) * 8;
      *(uint4*)&Bs_hi[n * LDA + kq] = *(const uint4*)(Wh + (size_t)n * K + kc + kq);
      *(uint4*)&Bs_lo[n * LDA + kq] = *(const uint4*)(Wl + (size_t)n * K + kc + kq);
    }
    __syncthreads();

    short8 ah[2], al[2];
    #pragma unroll
    for (int rt = 0; rt < 2; rt++) {
      int m = wave * 32 + rt * 16 + m16;
      ah[rt] = *(const short8*)&As_hi[m * LDA + quad * 8];
      al[rt] = *(const short8*)&As_lo[m * LDA + quad * 8];
    }
    #pragma unroll
    for (int ct = 0; ct < NCT; ct++) {
      int n = ct * 16 + m16;
      short8 bh = *(const short8*)&Bs_hi[n * LDA + quad * 8];
      short8 bl = *(const short8*)&Bs_lo[n * LDA + quad * 8];
      #pragma unroll
      for (int rt = 0; rt < 2; rt++) {
        acc[rt][ct] = __builtin_amdgcn_mfma_f32_16x16x32_bf16(ah[rt], bh, acc[rt][ct], 0, 0, 0);
        acc[rt][ct] = __builtin_amdgcn_mfma_f32_16x16x32_bf16(ah[rt], bl, acc[rt][ct], 0, 0, 0);
        acc[rt][ct] = __builtin_amdgcn_mfma_f32_16x16x32_bf16(al[rt], bh, acc[rt][ct], 0, 0, 0);
      }
    }
  }
  // epilogue: C/D layout col=lane&15, row=quad*4+reg
  #pragma unroll
  for (int ct = 0; ct < NCT; ct++) {
    int col = ct * 16 + m16;
    float bs = b[col] + b[DO + col] + b[2 * DO + col];
    #pragma unroll
    for (int rt = 0; rt < 2; rt++) {
      #pragma unroll
      for (int v = 0; v < 4; v++) {
        int row = m0 + wave * 32 + rt * 16 + quad * 4 + v;
        if (row < N_NODES) {
          float o = acc[rt][ct][v] + bs;
          if (apply_relu) o = fmaxf(o, 0.f);
          out[(size_t)row * DO + col] = o;
        }
      }
    }
  }
}

// ---------------- launch ----------------

extern "C" void kernel_launch(void* const* d_in, const int* in_sizes, int n_in,
                              void* d_out, int out_size, void* d_ws, size_t ws_size,
                              hipStream_t stream) {
  const float* x   = (const float*)d_in[0];
  const int*   src = (const int*)d_in[1];
  const int*   dst = (const int*)d_in[2];
  const float* Wl6[6]; const float* bl[6];
  for (int i = 0; i < 6; i++) { Wl6[i] = (const float*)d_in[3 + 2*i]; bl[i] = (const float*)d_in[4 + 2*i]; }

  // Workspace ~250.5 MB of the 256 MiB budget.
  // pos/excl alias agg_hi (dead before first agg_kernel write).
  char* ws = (char*)d_ws;
  size_t off = 0;
  auto take = [&](size_t bytes) -> char* {
    char* p = ws + off;
    off = (off + bytes + 255) & ~(size_t)255;
    return p;
  };
  float*  h       = (float*)take((size_t)N_NODES * 128 * 4);
  ushort* agg_hi  = (ushort*)take((size_t)N_NODES * 384 * 2);
  ushort* agg_lo  = (ushort*)take((size_t)N_NODES * 384 * 2);
  int*    deg     = (int*)  take((size_t)2 * N_REL * N_NODES * 4);
  int*    deg_out = deg;
  int*    deg_in  = deg + N_REL * N_NODES;
  float*  inv_out = (float*)take((size_t)N_REL * N_NODES * 4);
  float*  inv_in  = (float*)take((size_t)N_REL * N_NODES * 4);
  int*    row_off = (int*)  take((size_t)N_REL * (N_NODES + 1) * 4);
  int*    part    = (int*)  take((size_t)N_REL * NCHUNK * 4);
  float2* s_sc    = (float2*)take((size_t)N_REL * N_EDGE * 8);
  ushort* Wt      = (ushort*)take((size_t)6 * 384 * 128 * 2 * 2);   // hi|lo per layer
  int*    pos     = (int*)agg_hi;
  int*    excl    = (int*)agg_hi + (size_t)N_REL * N_EDGE;
  (void)ws_size; (void)in_sizes; (void)n_in; (void)out_size;

  hipMemsetAsync(deg, 0, (size_t)2 * N_REL * N_NODES * 4, stream);

  const int eblocks = (N_REL * N_EDGE + 255) / 256;
  const int nblocks = (N_REL * N_NODES + 255) / 256;
  p1_kernel<<<eblocks, 256, 0, stream>>>(src, dst, deg_out, deg_in, pos);
  inv_kernel<<<nblocks, 256, 0, stream>>>(deg_out, deg_in, inv_out, inv_in);
  scan1_kernel<<<dim3(NCHUNK, 3), 1024, 0, stream>>>(deg_in, excl, part);
  scan2_kernel<<<3, 128, 0, stream>>>(part);
  scan3_kernel<<<dim3(NCHUNK + 1, 3), 1024, 0, stream>>>(excl, part, row_off);
  scatter_kernel<<<eblocks, 256, 0, stream>>>(src, dst, pos, inv_out, inv_in, row_off, s_sc);

  // per-layer weight planes (hi|lo, transposed [DO][384])
  ushort* Wh[6]; ushort* Wlo[6];
  {
    size_t woff = 0;
    for (int L = 0; L < 6; L++) {
      int DOv = (L < 5) ? 128 : 64;
      Wh[L]  = Wt + woff;  woff += (size_t)384 * DOv;
      Wlo[L] = Wt + woff;  woff += (size_t)384 * DOv;
      convw_kernel<<<(384 * DOv + 255) / 256, 256, 0, stream>>>(Wl6[L], Wh[L], Wlo[L], DOv);
    }
  }

  const int mtiles = (N_NODES + 127) / 128;
  const int agg_blocks = (N_NODES + 3) / 4;
  const float* h_in = x;
  for (int L = 0; L < 6; L++) {
    agg_kernel<<<dim3(agg_blocks, 3), 256, 0, stream>>>(h_in, s_sc, row_off, agg_hi, agg_lo);
    if (L < 5) {
      gemm_kernel<128><<<mtiles, 256, 0, stream>>>(agg_hi, agg_lo, Wh[L], Wlo[L], bl[L], h, 1);
      h_in = h;
    } else {
      gemm_kernel<64><<<mtiles, 256, 0, stream>>>(agg_hi, agg_lo, Wh[L], Wlo[L], bl[L], (float*)d_out, 0);
    }
  }
}

// Round 8
// 3039.150 us; speedup vs baseline: 1.3963x; 1.0202x over previous
//
#include <hip/hip_runtime.h>
#include <hip/hip_bf16.h>

constexpr int N_NODES = 100000;
constexpr int N_REL   = 3;
constexpr int N_EDGE  = 1600000;
constexpr int NCHUNK  = (N_NODES + 1023) / 1024;   // 98

typedef __attribute__((ext_vector_type(8))) short short8;
typedef __attribute__((ext_vector_type(4))) float f32x4;

__device__ inline ushort f2bf(float x) {            // round-to-nearest-even bf16
  unsigned u = __float_as_uint(x);
  unsigned r = u + 0x7FFFu + ((u >> 16) & 1u);
  return (ushort)(r >> 16);
}
__device__ inline float bf2f(ushort h) { return __uint_as_float(((unsigned)h) << 16); }

// ---------------- graph preprocessing ----------------

__global__ void p1_kernel(const int* __restrict__ src, const int* __restrict__ dst,
                          int* __restrict__ deg_out, int* __restrict__ deg_in,
                          int* __restrict__ pos) {
  int tid = blockIdx.x * blockDim.x + threadIdx.x;
  if (tid >= N_REL * N_EDGE) return;
  int r = tid / N_EDGE;
  pos[tid] = atomicAdd(&deg_in[r * N_NODES + dst[tid]], 1);
  atomicAdd(&deg_out[r * N_NODES + src[tid]], 1);
}

__global__ void inv_kernel(const int* __restrict__ deg_out, const int* __restrict__ deg_in,
                           float* __restrict__ inv_out, float* __restrict__ inv_in) {
  int i = blockIdx.x * blockDim.x + threadIdx.x;
  if (i >= N_REL * N_NODES) return;
  inv_out[i] = rsqrtf(fmaxf((float)deg_out[i], 1.0f));
  inv_in[i]  = rsqrtf(fmaxf((float)deg_in[i],  1.0f));
}

__global__ void scan1_kernel(const int* __restrict__ deg_in, int* __restrict__ excl,
                             int* __restrict__ part) {
  int r = blockIdx.y;
  int i = blockIdx.x * 1024 + threadIdx.x;
  int v = (i < N_NODES) ? deg_in[r * N_NODES + i] : 0;
  __shared__ int sm[1024];
  sm[threadIdx.x] = v;
  __syncthreads();
  for (int off = 1; off < 1024; off <<= 1) {
    int t = (threadIdx.x >= (unsigned)off) ? sm[threadIdx.x - off] : 0;
    __syncthreads();
    sm[threadIdx.x] += t;
    __syncthreads();
  }
  if (i < N_NODES) excl[r * N_NODES + i] = sm[threadIdx.x] - v;
  if (threadIdx.x == 1023) part[r * NCHUNK + blockIdx.x] = sm[1023];
}

__global__ void scan2_kernel(int* __restrict__ part) {
  int r = blockIdx.x;
  int* p = part + r * NCHUNK;
  __shared__ int sm[128];
  int tid = threadIdx.x;
  int v = (tid < NCHUNK) ? p[tid] : 0;
  sm[tid] = v;
  __syncthreads();
  for (int off = 1; off < 128; off <<= 1) {
    int t = (tid >= off) ? sm[tid - off] : 0;
    __syncthreads();
    sm[tid] += t;
    __syncthreads();
  }
  if (tid < NCHUNK) p[tid] = sm[tid] - v;
}

__global__ void scan3_kernel(const int* __restrict__ excl, const int* __restrict__ part,
                             int* __restrict__ row_off) {
  int r = blockIdx.y;
  int i = blockIdx.x * 1024 + threadIdx.x;
  if (i < N_NODES) row_off[r * (N_NODES + 1) + i] = excl[r * N_NODES + i] + part[r * NCHUNK + (i >> 10)];
  if (i == N_NODES) row_off[r * (N_NODES + 1) + N_NODES] = N_EDGE;
}

__global__ void scatter_kernel(const int* __restrict__ src, const int* __restrict__ dst,
                               const int* __restrict__ pos,
                               const float* __restrict__ inv_out, const float* __restrict__ inv_in,
                               const int* __restrict__ row_off, float2* __restrict__ sorted_sc) {
  int tid = blockIdx.x * blockDim.x + threadIdx.x;
  if (tid >= N_REL * N_EDGE) return;
  int r = tid / N_EDGE;
  int s = src[tid], d = dst[tid];
  int o = row_off[r * (N_NODES + 1) + d] + pos[tid];
  float coef = inv_out[r * N_NODES + s] * inv_in[r * N_NODES + d];
  sorted_sc[(size_t)r * N_EDGE + o] = make_float2(__int_as_float(s), coef);
}

// per-layer weight preconvert: W[k][c] fp32 -> transposed hi/lo bf16 planes Wt[c][k]
__global__ void convw_kernel(const float* __restrict__ W, ushort* __restrict__ Wh,
                             ushort* __restrict__ Wl, int DOv) {
  int idx = blockIdx.x * 256 + threadIdx.x;
  if (idx >= 384 * DOv) return;
  int k = idx / DOv, c = idx % DOv;
  float v = W[idx];
  ushort hh = f2bf(v);
  Wh[c * 384 + k] = hh;
  Wl[c * 384 + k] = f2bf(v - bf2f(hh));
}

// ---------------- per-layer kernels ----------------

// Gather-first: acc[n][r*128+c] = sum coef_e * h[src_e][c] (fp32),
// emitted as bf16 hi/lo planes so the GEMM stages without conversion.
// Whole-wave float2 per edge, 8 edges in flight (deg>=8 covers ~99% of
// Poisson(16) lists — the old 16-edge gate left ~46% at depth 1), staged tail.
__launch_bounds__(256)
__global__ void agg_kernel(const float* __restrict__ h, const float2* __restrict__ sc,
                           const int* __restrict__ row_off,
                           ushort* __restrict__ agg_hi, ushort* __restrict__ agg_lo) {
  int r    = blockIdx.y;
  int node = blockIdx.x * 4 + ((int)threadIdx.x >> 6);
  int lane = (int)threadIdx.x & 63;
  if (node >= N_NODES) return;
  const int* ro = row_off + r * (N_NODES + 1);
  int beg = ro[node], end = ro[node + 1];
  const float2* scp = sc + (size_t)r * N_EDGE;
  const float2* hp  = (const float2*)h;    // row = 64 float2
  float2 acc = make_float2(0.f, 0.f);
  int e = beg;
  for (; e + 8 <= end; e += 8) {
    float2 q[8];
    #pragma unroll
    for (int j = 0; j < 8; j++) q[j] = scp[e + j];
    float2 v[8];
    #pragma unroll
    for (int j = 0; j < 8; j++) v[j] = hp[(size_t)__float_as_int(q[j].x) * 64 + lane];
    #pragma unroll
    for (int j = 0; j < 8; j++) {
      acc.x = fmaf(q[j].y, v[j].x, acc.x);
      acc.y = fmaf(q[j].y, v[j].y, acc.y);
    }
  }
  if (e + 4 <= end) {
    float2 q[4];
    #pragma unroll
    for (int j = 0; j < 4; j++) q[j] = scp[e + j];
    float2 v[4];
    #pragma unroll
    for (int j = 0; j < 4; j++) v[j] = hp[(size_t)__float_as_int(q[j].x) * 64 + lane];
    #pragma unroll
    for (int j = 0; j < 4; j++) {
      acc.x = fmaf(q[j].y, v[j].x, acc.x);
      acc.y = fmaf(q[j].y, v[j].y, acc.y);
    }
    e += 4;
  }
  if (e + 2 <= end) {
    float2 q0 = scp[e], q1 = scp[e + 1];
    float2 v0 = hp[(size_t)__float_as_int(q0.x) * 64 + lane];
    float2 v1 = hp[(size_t)__float_as_int(q1.x) * 64 + lane];
    acc.x = fmaf(q0.y, v0.x, acc.x); acc.y = fmaf(q0.y, v0.y, acc.y);
    acc.x = fmaf(q1.y, v1.x, acc.x); acc.y = fmaf(q1.y, v1.y, acc.y);
    e += 2;
  }
  if (e < end) {
    float2 q = scp[e];
    float2 v = hp[(size_t)__float_as_int(q.x) * 64 + lane];
    acc.x = fmaf(q.y, v.x, acc.x); acc.y = fmaf(q.y, v.y, acc.y);
  }
  ushort2 hi, lo;
  hi.x = f2bf(acc.x); lo.x = f2bf(acc.x - bf2f(hi.x));
  hi.y = f2bf(acc.y); lo.y = f2bf(acc.y - bf2f(hi.y));
  size_t base = (size_t)node * 384 + r * 128 + lane * 2;
  *(ushort2*)(agg_hi + base) = hi;
  *(ushort2*)(agg_lo + base) = lo;
}

// bf16x3 split MFMA GEMM, conversion-free staging:
// out = relu?( A(hi+lo)[128-tile][384] @ W(hi+lo)[384][DO] + sum_r b )
// A*W ~= Ah*Wh + Ah*Wl + Al*Wh. LDS rows padded to 40 ushorts.
template<int DO>
__launch_bounds__(256)
__global__ void gemm_kernel(const ushort* __restrict__ Ah, const ushort* __restrict__ Al,
                            const ushort* __restrict__ Wh, const ushort* __restrict__ Wl,
                            const float* __restrict__ b, float* __restrict__ out, int apply_relu) {
  constexpr int K   = 384;
  constexpr int KC  = 32;
  constexpr int NCT = DO / 16;
  constexpr int LDA = 40;
  __shared__ ushort As_hi[128 * LDA], As_lo[128 * LDA];
  __shared__ ushort Bs_hi[DO * LDA],  Bs_lo[DO * LDA];
  int tid  = threadIdx.x;
  int wave = tid >> 6, lane = tid & 63;
  int quad = lane >> 4, m16 = lane & 15;
  int m0 = blockIdx.x * 128;

  f32x4 acc[2][NCT];
  #pragma unroll
  for (int rt = 0; rt < 2; rt++)
    #pragma unroll
    for (int ct = 0; ct < NCT; ct++) acc[rt][ct] = (f32x4){0.f, 0.f, 0.f, 0.f};

  for (int kc = 0; kc < K; kc += KC) {
    __syncthreads();
    // A tile: 128 rows x 32 k, two planes, pure 16B copies
    #pragma unroll
    for (int it = 0; it < 2; it++) {
      int idx = it * 256 + tid;            // 0..511
      int row = idx >> 2, kq = (idx & 3) * 8;
      uint4 vh = make_uint4(0u, 0u, 0u, 0u), vl = make_uint4(0u, 0u, 0u, 0u);
      if (m0 + row < N_NODES) {
        vh = *(const uint4*)(Ah + (size_t)(m0 + row) * K + kc + kq);
        vl = *(const uint4*)(Al + (size_t)(m0 + row) * K + kc + kq);
      }
      *(uint4*)&As_hi[row * LDA + kq] = vh;
      *(uint4*)&As_lo[row * LDA + kq] = vl;
    }
    // B tile from pretransposed W: DO rows x 32 k, two planes
    #pragma unroll
    for (int it = 0; it < DO / 64; it++) {
      int idx = it * 256 + tid;            // 0..DO*4-1
      int n = idx >> 2, kq = (idx & 3) * 8;
      *(uint4*)&Bs_hi[n * LDA + kq] = *(const uint4*)(Wh + (size_t)n * K + kc + kq);
      *(uint4*)&Bs_lo[n * LDA + kq] = *(const uint4*)(Wl + (size_t)n * K + kc + kq);
    }
    __syncthreads();

    short8 ah[2], al[2];
    #pragma unroll
    for (int rt = 0; rt < 2; rt++) {
      int m = wave * 32 + rt * 16 + m16;
      ah[rt] = *(const short8*)&As_hi[m * LDA + quad * 8];
      al[rt] = *(const short8*)&As_lo[m * LDA + quad * 8];
    }
    #pragma unroll
    for (int ct = 0; ct < NCT; ct++) {
      int n = ct * 16 + m16;
      short8 bh = *(const short8*)&Bs_hi[n * LDA + quad * 8];
      short8 bl = *(const short8*)&Bs_lo[n * LDA + quad * 8];
      #pragma unroll
      for (int rt = 0; rt < 2; rt++) {
        acc[rt][ct] = __builtin_amdgcn_mfma_f32_16x16x32_bf16(ah[rt], bh, acc[rt][ct], 0, 0, 0);
        acc[rt][ct] = __builtin_amdgcn_mfma_f32_16x16x32_bf16(ah[rt], bl, acc[rt][ct], 0, 0, 0);
        acc[rt][ct] = __builtin_amdgcn_mfma_f32_16x16x32_bf16(al[rt], bh, acc[rt][ct], 0, 0, 0);
      }
    }
  }
  // epilogue: C/D layout col=lane&15, row=quad*4+reg
  #pragma unroll
  for (int ct = 0; ct < NCT; ct++) {
    int col = ct * 16 + m16;
    float bs = b[col] + b[DO + col] + b[2 * DO + col];
    #pragma unroll
    for (int rt = 0; rt < 2; rt++) {
      #pragma unroll
      for (int v = 0; v < 4; v++) {
        int row = m0 + wave * 32 + rt * 16 + quad * 4 + v;
        if (row < N_NODES) {
          float o = acc[rt][ct][v] + bs;
          if (apply_relu) o = fmaxf(o, 0.f);
          out[(size_t)row * DO + col] = o;
        }
      }
    }
  }
}

// ---------------- launch ----------------

extern "C" void kernel_launch(void* const* d_in, const int* in_sizes, int n_in,
                              void* d_out, int out_size, void* d_ws, size_t ws_size,
                              hipStream_t stream) {
  const float* x   = (const float*)d_in[0];
  const int*   src = (const int*)d_in[1];
  const int*   dst = (const int*)d_in[2];
  const float* Wl6[6]; const float* bl[6];
  for (int i = 0; i < 6; i++) { Wl6[i] = (const float*)d_in[3 + 2*i]; bl[i] = (const float*)d_in[4 + 2*i]; }

  // Workspace ~250.5 MB of the 256 MiB budget.
  // pos/excl alias agg_hi (dead before first agg_kernel write).
  char* ws = (char*)d_ws;
  size_t off = 0;
  auto take = [&](size_t bytes) -> char* {
    char* p = ws + off;
    off = (off + bytes + 255) & ~(size_t)255;
    return p;
  };
  float*  h       = (float*)take((size_t)N_NODES * 128 * 4);
  ushort* agg_hi  = (ushort*)take((size_t)N_NODES * 384 * 2);
  ushort* agg_lo  = (ushort*)take((size_t)N_NODES * 384 * 2);
  int*    deg     = (int*)  take((size_t)2 * N_REL * N_NODES * 4);
  int*    deg_out = deg;
  int*    deg_in  = deg + N_REL * N_NODES;
  float*  inv_out = (float*)take((size_t)N_REL * N_NODES * 4);
  float*  inv_in  = (float*)take((size_t)N_REL * N_NODES * 4);
  int*    row_off = (int*)  take((size_t)N_REL * (N_NODES + 1) * 4);
  int*    part    = (int*)  take((size_t)N_REL * NCHUNK * 4);
  float2* s_sc    = (float2*)take((size_t)N_REL * N_EDGE * 8);
  ushort* Wt      = (ushort*)take((size_t)6 * 384 * 128 * 2 * 2);   // hi|lo per layer
  int*    pos     = (int*)agg_hi;
  int*    excl    = (int*)agg_hi + (size_t)N_REL * N_EDGE;
  (void)ws_size; (void)in_sizes; (void)n_in; (void)out_size;

  hipMemsetAsync(deg, 0, (size_t)2 * N_REL * N_NODES * 4, stream);

  const int eblocks = (N_REL * N_EDGE + 255) / 256;
  const int nblocks = (N_REL * N_NODES + 255) / 256;
  p1_kernel<<<eblocks, 256, 0, stream>>>(src, dst, deg_out, deg_in, pos);
  inv_kernel<<<nblocks, 256, 0, stream>>>(deg_out, deg_in, inv_out, inv_in);
  scan1_kernel<<<dim3(NCHUNK, 3), 1024, 0, stream>>>(deg_in, excl, part);
  scan2_kernel<<<3, 128, 0, stream>>>(part);
  scan3_kernel<<<dim3(NCHUNK + 1, 3), 1024, 0, stream>>>(excl, part, row_off);
  scatter_kernel<<<eblocks, 256, 0, stream>>>(src, dst, pos, inv_out, inv_in, row_off, s_sc);

  // per-layer weight planes (hi|lo, transposed [DO][384])
  ushort* Wh[6]; ushort* Wlo[6];
  {
    size_t woff = 0;
    for (int L = 0; L < 6; L++) {
      int DOv = (L < 5) ? 128 : 64;
      Wh[L]  = Wt + woff;  woff += (size_t)384 * DOv;
      Wlo[L] = Wt + woff;  woff += (size_t)384 * DOv;
      convw_kernel<<<(384 * DOv + 255) / 256, 256, 0, stream>>>(Wl6[L], Wh[L], Wlo[L], DOv);
    }
  }

  const int mtiles = (N_NODES + 127) / 128;
  const int agg_blocks = (N_NODES + 3) / 4;
  const float* h_in = x;
  for (int L = 0; L < 6; L++) {
    agg_kernel<<<dim3(agg_blocks, 3), 256, 0, stream>>>(h_in, s_sc, row_off, agg_hi, agg_lo);
    if (L < 5) {
      gemm_kernel<128><<<mtiles, 256, 0, stream>>>(agg_hi, agg_lo, Wh[L], Wlo[L], bl[L], h, 1);
      h_in = h;
    } else {
      gemm_kernel<64><<<mtiles, 256, 0, stream>>>(agg_hi, agg_lo, Wh[L], Wlo[L], bl[L], (float*)d_out, 0);
    }
  }
}